// Round 2
// baseline (3088.204 us; speedup 1.0000x reference)
//
#include <hip/hip_runtime.h>
#include <hip/hip_bf16.h>

// SPRGraphNet: embed -> 2x SAGEConv(mean) -> mean-pool per graph -> linear(64->10)
// Float inputs may be fp32 or bf16 depending on harness config; a runtime
// detect kernel disambiguates (reading fp32 data as bf16 yields garbage with
// |v|>100 / NaN among odd elements; real bf16 params are all |v|<1).
// Internal compute in fp32; output dtype follows the detected input dtype.

struct WParams {
    const void* p[10];
    int off[11];
};

__device__ __forceinline__ float loadf(const void* p, int i, int f32) {
    return f32 ? ((const float*)p)[i]
               : __bfloat162float(((const __hip_bfloat16*)p)[i]);
}

static __global__ void detect_kernel(const void* probe, int n_bf16, int* flag) {
    __shared__ int bad;
    if (threadIdx.x == 0) bad = 0;
    __syncthreads();
    const __hip_bfloat16* p = (const __hip_bfloat16*)probe;
    int lbad = 0;
    for (int i = threadIdx.x; i < n_bf16; i += blockDim.x) {
        float v = __bfloat162float(p[i]);
        if (!(fabsf(v) <= 100.0f)) lbad = 1;   // catches huge AND NaN
    }
    if (lbad) atomicOr(&bad, 1);
    __syncthreads();
    if (threadIdx.x == 0) *flag = bad;         // 1 => inputs are fp32
}

static __global__ void convert_kernel(WParams wp, const int* __restrict__ flag,
                                      float* __restrict__ dst, int total) {
    int gid = blockIdx.x * blockDim.x + threadIdx.x;
    if (gid >= total) return;
    int f32 = *flag;
    int s = 0;
    while (gid >= wp.off[s + 1]) ++s;
    dst[gid] = loadf(wp.p[s], gid - wp.off[s], f32);
}

static __global__ void embed_kernel(const int* __restrict__ x,
                                    const float* __restrict__ semb,
                                    const float* __restrict__ cemb,
                                    float* __restrict__ h, int n_nodes) {
    int gid = blockIdx.x * blockDim.x + threadIdx.x;
    int node = gid >> 6, col = gid & 63;
    if (node >= n_nodes) return;
    float v;
    if (col < 32) {
        int s = x[node * 2];
        v = semb[s * 32 + col];
    } else {
        int c = x[node * 2 + 1];
        v = cemb[c * 32 + (col - 32)];
    }
    h[node * 64 + col] = v;
}

static __global__ void count_kernel(const int* __restrict__ tgt,
                                    int* __restrict__ cnt, int n_edges) {
    int e = blockIdx.x * blockDim.x + threadIdx.x;
    if (e < n_edges) atomicAdd(&cnt[tgt[e]], 1);
}

// One 16-thread group per edge; each thread moves a float4 (4 cols).
static __global__ void scatter_kernel(const float* __restrict__ h,
                                      const int* __restrict__ src,
                                      const int* __restrict__ tgt,
                                      float* __restrict__ agg, int n_edges) {
    int gid = blockIdx.x * blockDim.x + threadIdx.x;
    int e = gid >> 4, j = gid & 15;
    if (e >= n_edges) return;
    int s = src[e], t = tgt[e];
    const float4 v = *reinterpret_cast<const float4*>(h + (size_t)s * 64 + j * 4);
    float* base = agg + (size_t)t * 64 + j * 4;
    atomicAdd(base + 0, v.x);
    atomicAdd(base + 1, v.y);
    atomicAdd(base + 2, v.z);
    atomicAdd(base + 3, v.w);
}

// h = relu((agg/cnt) @ wl + h @ wr + b), in place (row i depends only on row i).
// Block: 256 threads = 4 node-rows x 64 cols; 64 nodes per block (16 iters).
static __global__ __launch_bounds__(256) void layer_kernel(
        float* __restrict__ h, const float* __restrict__ agg,
        const int* __restrict__ cnt,
        const float* __restrict__ wl, const float* __restrict__ wr,
        const float* __restrict__ b, int n_nodes) {
    __shared__ float wlS[64 * 64];
    __shared__ float wrS[64 * 64];
    __shared__ float aS[4][64];
    __shared__ float hS[4][64];
    int t = threadIdx.x;
    for (int i = t; i < 64 * 64; i += 256) {
        wlS[i] = wl[i];
        wrS[i] = wr[i];
    }
    int r = t >> 6, o = t & 63;
    float bias_o = b[o];
    __syncthreads();
    int base = blockIdx.x * 64;
    for (int it = 0; it < 16; ++it) {
        int node = base + it * 4 + r;
        if (node < n_nodes) {
            float inv = 1.0f / fmaxf((float)cnt[node], 1.0f);
            aS[r][o] = agg[(size_t)node * 64 + o] * inv;
            hS[r][o] = h[(size_t)node * 64 + o];
        }
        __syncthreads();
        if (node < n_nodes) {
            float acc = bias_o;
#pragma unroll
            for (int k = 0; k < 64; ++k) {
                acc = fmaf(aS[r][k], wlS[k * 64 + o], acc);
                acc = fmaf(hS[r][k], wrS[k * 64 + o], acc);
            }
            h[(size_t)node * 64 + o] = fmaxf(acc, 0.0f);
        }
        __syncthreads();
    }
}

// batch is sorted: binary-search [start,end) per graph; mean-pool then classify.
static __global__ __launch_bounds__(256) void pool_classify_kernel(
        const float* __restrict__ h, const int* __restrict__ batch,
        const float* __restrict__ wc, const float* __restrict__ bc,
        void* __restrict__ out, const int* __restrict__ flag, int n_nodes) {
    int g = blockIdx.x;
    int t = threadIdx.x;
    int lo = 0, hi = n_nodes;
    while (lo < hi) { int mid = (lo + hi) >> 1; if (batch[mid] < g) lo = mid + 1; else hi = mid; }
    int start = lo;
    hi = n_nodes;
    while (lo < hi) { int mid = (lo + hi) >> 1; if (batch[mid] < g + 1) lo = mid + 1; else hi = mid; }
    int end = lo;

    int r = t >> 6, o = t & 63;
    float partial = 0.0f;
    for (int n = start + r; n < end; n += 4) partial += h[(size_t)n * 64 + o];
    __shared__ float sred[4][64];
    __shared__ float pooled[64];
    sred[r][o] = partial;
    __syncthreads();
    if (r == 0) {
        float cntf = fmaxf((float)(end - start), 1.0f);
        pooled[o] = (sred[0][o] + sred[1][o] + sred[2][o] + sred[3][o]) / cntf;
    }
    __syncthreads();
    if (t < 10) {
        float acc = bc[t];
#pragma unroll
        for (int k = 0; k < 64; ++k)
            acc = fmaf(pooled[k], wc[k * 10 + t], acc);
        if (*flag) ((float*)out)[g * 10 + t] = acc;
        else       ((__hip_bfloat16*)out)[g * 10 + t] = __float2bfloat16(acc);
    }
}

extern "C" void kernel_launch(void* const* d_in, const int* in_sizes, int n_in,
                              void* d_out, int out_size, void* d_ws, size_t ws_size,
                              hipStream_t stream) {
    const int* x          = (const int*)d_in[0];
    const int* edge_index = (const int*)d_in[1];
    const int* batch      = (const int*)d_in[2];
    // d_in[3] = num_graphs scalar (device)

    const int N = in_sizes[2];        // N_NODES
    const int E = in_sizes[1] / 2;    // edge_index is (2, E)
    const int G = out_size / 10;      // num_graphs

    // workspace layout (fp32)
    float* h    = (float*)d_ws;
    float* agg  = h + (size_t)N * 64;
    int*   cnt  = (int*)(agg + (size_t)N * 64);
    float* wbuf = (float*)(cnt + N);

    // float params: indices 4..13 in d_in
    WParams wp;
    int off = 0;
    for (int i = 0; i < 10; ++i) {
        wp.p[i] = d_in[4 + i];
        wp.off[i] = off;
        off += in_sizes[4 + i];
    }
    wp.off[10] = off;
    const int wtotal = off;

    float* semb_f = wbuf + wp.off[0];
    float* cemb_f = wbuf + wp.off[1];
    float* w1l_f  = wbuf + wp.off[2];
    float* w1r_f  = wbuf + wp.off[3];
    float* b1_f   = wbuf + wp.off[4];
    float* w2l_f  = wbuf + wp.off[5];
    float* w2r_f  = wbuf + wp.off[6];
    float* b2_f   = wbuf + wp.off[7];
    float* wc_f   = wbuf + wp.off[8];
    float* bc_f   = wbuf + wp.off[9];
    int*   flag   = (int*)(wbuf + wtotal);

    const int* src = edge_index;
    const int* tgt = edge_index + E;
    const int scatter_blocks = (int)(((size_t)E * 16 + 255) / 256);

    detect_kernel<<<1, 256, 0, stream>>>(d_in[4], 1024, flag);
    convert_kernel<<<(wtotal + 255) / 256, 256, 0, stream>>>(wp, flag, wbuf, wtotal);

    // zero agg + cnt (contiguous)
    hipMemsetAsync(agg, 0, (size_t)N * 64 * sizeof(float) + (size_t)N * sizeof(int), stream);

    embed_kernel<<<(N * 64 + 255) / 256, 256, 0, stream>>>(x, semb_f, cemb_f, h, N);
    count_kernel<<<(E + 255) / 256, 256, 0, stream>>>(tgt, cnt, E);

    // layer 1
    scatter_kernel<<<scatter_blocks, 256, 0, stream>>>(h, src, tgt, agg, E);
    layer_kernel<<<(N + 63) / 64, 256, 0, stream>>>(h, agg, cnt, w1l_f, w1r_f, b1_f, N);

    // layer 2
    hipMemsetAsync(agg, 0, (size_t)N * 64 * sizeof(float), stream);
    scatter_kernel<<<scatter_blocks, 256, 0, stream>>>(h, src, tgt, agg, E);
    layer_kernel<<<(N + 63) / 64, 256, 0, stream>>>(h, agg, cnt, w2l_f, w2r_f, b2_f, N);

    // pool + classify
    pool_classify_kernel<<<G, 256, 0, stream>>>(h, batch, wc_f, bc_f, d_out, flag, N);
}

// Round 3
// 600.067 us; speedup vs baseline: 5.1464x; 5.1464x over previous
//
#include <hip/hip_runtime.h>
#include <hip/hip_bf16.h>

// SPRGraphNet: embed -> 2x SAGEConv(mean) -> mean-pool per graph -> linear(64->10)
// Inputs detected fp32 (round 2). Aggregation via per-launch CSR + gather
// (round 2 showed scatter atomics = 88% of runtime at 0.86% VALUBusy).

struct WParams {
    const void* p[10];
    int off[11];
};

__device__ __forceinline__ float loadf(const void* p, int i, int f32) {
    return f32 ? ((const float*)p)[i]
               : __bfloat162float(((const __hip_bfloat16*)p)[i]);
}

static __global__ void detect_kernel(const void* probe, int n_bf16, int* flag) {
    __shared__ int bad;
    if (threadIdx.x == 0) bad = 0;
    __syncthreads();
    const __hip_bfloat16* p = (const __hip_bfloat16*)probe;
    int lbad = 0;
    for (int i = threadIdx.x; i < n_bf16; i += blockDim.x) {
        float v = __bfloat162float(p[i]);
        if (!(fabsf(v) <= 100.0f)) lbad = 1;   // catches huge AND NaN
    }
    if (lbad) atomicOr(&bad, 1);
    __syncthreads();
    if (threadIdx.x == 0) *flag = bad;         // 1 => inputs are fp32
}

static __global__ void convert_kernel(WParams wp, const int* __restrict__ flag,
                                      float* __restrict__ dst, int total) {
    int gid = blockIdx.x * blockDim.x + threadIdx.x;
    if (gid >= total) return;
    int f32 = *flag;
    int s = 0;
    while (gid >= wp.off[s + 1]) ++s;
    dst[gid] = loadf(wp.p[s], gid - wp.off[s], f32);
}

static __global__ void embed_kernel(const int* __restrict__ x,
                                    const float* __restrict__ semb,
                                    const float* __restrict__ cemb,
                                    float* __restrict__ h, int n_nodes) {
    int gid = blockIdx.x * blockDim.x + threadIdx.x;
    int node = gid >> 6, col = gid & 63;
    if (node >= n_nodes) return;
    float v;
    if (col < 32) {
        int s = x[node * 2];
        v = semb[s * 32 + col];
    } else {
        int c = x[node * 2 + 1];
        v = cemb[c * 32 + (col - 32)];
    }
    h[node * 64 + col] = v;
}

static __global__ void count_kernel(const int* __restrict__ tgt,
                                    int* __restrict__ cnt, int n_edges) {
    int e = blockIdx.x * blockDim.x + threadIdx.x;
    if (e < n_edges) atomicAdd(&cnt[tgt[e]], 1);
}

// ---- prefix-sum (exclusive) over cnt -> rowptr[0..n], 3 kernels ----
static __global__ __launch_bounds__(256) void scan1_kernel(
        const int* __restrict__ cnt, int* __restrict__ tmp,
        int* __restrict__ bsum, int n) {
    __shared__ int s[256];
    int t = threadIdx.x;
    int i = blockIdx.x * 256 + t;
    s[t] = (i < n) ? cnt[i] : 0;
    __syncthreads();
#pragma unroll
    for (int d = 1; d < 256; d <<= 1) {
        int x = (t >= d) ? s[t - d] : 0;
        __syncthreads();
        s[t] += x;
        __syncthreads();
    }
    if (i < n) tmp[i] = s[t];                 // inclusive scan within block
    if (t == 255) bsum[blockIdx.x] = s[255];
}

static __global__ __launch_bounds__(1024) void scan2_kernel(
        int* __restrict__ bsum, int nb) {     // in-place inclusive scan, nb <= 1024
    __shared__ int s[1024];
    int t = threadIdx.x;
    s[t] = (t < nb) ? bsum[t] : 0;
    __syncthreads();
#pragma unroll
    for (int d = 1; d < 1024; d <<= 1) {
        int x = (t >= d) ? s[t - d] : 0;
        __syncthreads();
        s[t] += x;
        __syncthreads();
    }
    if (t < nb) bsum[t] = s[t];
}

static __global__ __launch_bounds__(256) void scan3_kernel(
        const int* __restrict__ tmp, const int* __restrict__ bsum,
        int* __restrict__ rowptr, int n) {
    int i = blockIdx.x * 256 + threadIdx.x;
    if (i >= n) return;
    int base = (blockIdx.x > 0) ? bsum[blockIdx.x - 1] : 0;
    rowptr[i + 1] = tmp[i] + base;            // exclusive: rowptr[k] = sum cnt[0..k-1]
    if (i == 0) rowptr[0] = 0;
}

static __global__ void fill_kernel(const int* __restrict__ src,
                                   const int* __restrict__ tgt,
                                   const int* __restrict__ rowptr,
                                   int* __restrict__ fillpos,
                                   int* __restrict__ csr_src, int n_edges) {
    int e = blockIdx.x * blockDim.x + threadIdx.x;
    if (e >= n_edges) return;
    int t = tgt[e];
    int pos = rowptr[t] + atomicAdd(&fillpos[t], 1);
    csr_src[pos] = src[e];
}

// One wave per node; lane = feature column. agg[n] = mean of h[src] over in-edges.
static __global__ __launch_bounds__(256) void gather_kernel(
        const float* __restrict__ h, const int* __restrict__ rowptr,
        const int* __restrict__ csr_src, float* __restrict__ agg, int n_nodes) {
    int node = (blockIdx.x * 256 + threadIdx.x) >> 6;
    int lane = threadIdx.x & 63;
    if (node >= n_nodes) return;
    int beg = rowptr[node], end = rowptr[node + 1];
    float a0 = 0.f, a1 = 0.f, a2 = 0.f, a3 = 0.f;
    int i = beg;
    for (; i + 4 <= end; i += 4) {
        int s0 = csr_src[i], s1 = csr_src[i + 1];
        int s2 = csr_src[i + 2], s3 = csr_src[i + 3];
        a0 += h[(size_t)s0 * 64 + lane];
        a1 += h[(size_t)s1 * 64 + lane];
        a2 += h[(size_t)s2 * 64 + lane];
        a3 += h[(size_t)s3 * 64 + lane];
    }
    for (; i < end; ++i) a0 += h[(size_t)csr_src[i] * 64 + lane];
    float tot = (a0 + a1) + (a2 + a3);
    float inv = 1.0f / fmaxf((float)(end - beg), 1.0f);
    agg[(size_t)node * 64 + lane] = tot * inv;
}

// h = relu(agg @ wl + h @ wr + b), in place (row i depends only on row i).
static __global__ __launch_bounds__(256) void layer_kernel(
        float* __restrict__ h, const float* __restrict__ agg,
        const float* __restrict__ wl, const float* __restrict__ wr,
        const float* __restrict__ b, int n_nodes) {
    __shared__ float wlS[64 * 64];
    __shared__ float wrS[64 * 64];
    __shared__ float aS[4][64];
    __shared__ float hS[4][64];
    int t = threadIdx.x;
    for (int i = t; i < 64 * 64; i += 256) {
        wlS[i] = wl[i];
        wrS[i] = wr[i];
    }
    int r = t >> 6, o = t & 63;
    float bias_o = b[o];
    __syncthreads();
    int base = blockIdx.x * 64;
    for (int it = 0; it < 16; ++it) {
        int node = base + it * 4 + r;
        if (node < n_nodes) {
            aS[r][o] = agg[(size_t)node * 64 + o];
            hS[r][o] = h[(size_t)node * 64 + o];
        }
        __syncthreads();
        if (node < n_nodes) {
            float acc = bias_o;
#pragma unroll
            for (int k = 0; k < 64; ++k) {
                acc = fmaf(aS[r][k], wlS[k * 64 + o], acc);
                acc = fmaf(hS[r][k], wrS[k * 64 + o], acc);
            }
            h[(size_t)node * 64 + o] = fmaxf(acc, 0.0f);
        }
        __syncthreads();
    }
}

// batch is sorted: binary-search [start,end) per graph; mean-pool then classify.
static __global__ __launch_bounds__(256) void pool_classify_kernel(
        const float* __restrict__ h, const int* __restrict__ batch,
        const float* __restrict__ wc, const float* __restrict__ bc,
        void* __restrict__ out, const int* __restrict__ flag, int n_nodes) {
    int g = blockIdx.x;
    int t = threadIdx.x;
    int lo = 0, hi = n_nodes;
    while (lo < hi) { int mid = (lo + hi) >> 1; if (batch[mid] < g) lo = mid + 1; else hi = mid; }
    int start = lo;
    hi = n_nodes;
    while (lo < hi) { int mid = (lo + hi) >> 1; if (batch[mid] < g + 1) lo = mid + 1; else hi = mid; }
    int end = lo;

    int r = t >> 6, o = t & 63;
    float partial = 0.0f;
    for (int n = start + r; n < end; n += 4) partial += h[(size_t)n * 64 + o];
    __shared__ float sred[4][64];
    __shared__ float pooled[64];
    sred[r][o] = partial;
    __syncthreads();
    if (r == 0) {
        float cntf = fmaxf((float)(end - start), 1.0f);
        pooled[o] = (sred[0][o] + sred[1][o] + sred[2][o] + sred[3][o]) / cntf;
    }
    __syncthreads();
    if (t < 10) {
        float acc = bc[t];
#pragma unroll
        for (int k = 0; k < 64; ++k)
            acc = fmaf(pooled[k], wc[k * 10 + t], acc);
        if (*flag) ((float*)out)[g * 10 + t] = acc;
        else       ((__hip_bfloat16*)out)[g * 10 + t] = __float2bfloat16(acc);
    }
}

extern "C" void kernel_launch(void* const* d_in, const int* in_sizes, int n_in,
                              void* d_out, int out_size, void* d_ws, size_t ws_size,
                              hipStream_t stream) {
    const int* x          = (const int*)d_in[0];
    const int* edge_index = (const int*)d_in[1];
    const int* batch      = (const int*)d_in[2];

    const int N = in_sizes[2];        // N_NODES
    const int E = in_sizes[1] / 2;    // edge_index is (2, E)
    const int G = out_size / 10;      // num_graphs
    const int NB = (N + 255) / 256;   // scan blocks (<=1024 required)

    // workspace layout (fp32 / int32)
    float* h       = (float*)d_ws;
    float* agg     = h + (size_t)N * 64;
    int*   cnt     = (int*)(agg + (size_t)N * 64);
    int*   fillpos = cnt + N;                 // contiguous with cnt for one memset
    int*   rowptr  = fillpos + N;             // N+1
    int*   tmp     = rowptr + (N + 1);        // N
    int*   bsum    = tmp + N;                 // NB
    int*   csr_src = bsum + NB;               // E
    float* wbuf    = (float*)(csr_src + E);

    WParams wp;
    int off = 0;
    for (int i = 0; i < 10; ++i) {
        wp.p[i] = d_in[4 + i];
        wp.off[i] = off;
        off += in_sizes[4 + i];
    }
    wp.off[10] = off;
    const int wtotal = off;

    float* semb_f = wbuf + wp.off[0];
    float* cemb_f = wbuf + wp.off[1];
    float* w1l_f  = wbuf + wp.off[2];
    float* w1r_f  = wbuf + wp.off[3];
    float* b1_f   = wbuf + wp.off[4];
    float* w2l_f  = wbuf + wp.off[5];
    float* w2r_f  = wbuf + wp.off[6];
    float* b2_f   = wbuf + wp.off[7];
    float* wc_f   = wbuf + wp.off[8];
    float* bc_f   = wbuf + wp.off[9];
    int*   flag   = (int*)(wbuf + wtotal);

    const int* src = edge_index;
    const int* tgt = edge_index + E;

    detect_kernel<<<1, 256, 0, stream>>>(d_in[4], 1024, flag);
    convert_kernel<<<(wtotal + 255) / 256, 256, 0, stream>>>(wp, flag, wbuf, wtotal);

    // zero cnt + fillpos (contiguous)
    hipMemsetAsync(cnt, 0, (size_t)2 * N * sizeof(int), stream);

    embed_kernel<<<(N * 64 + 255) / 256, 256, 0, stream>>>(x, semb_f, cemb_f, h, N);
    count_kernel<<<(E + 255) / 256, 256, 0, stream>>>(tgt, cnt, E);

    // CSR build
    scan1_kernel<<<NB, 256, 0, stream>>>(cnt, tmp, bsum, N);
    scan2_kernel<<<1, 1024, 0, stream>>>(bsum, NB);
    scan3_kernel<<<NB, 256, 0, stream>>>(tmp, bsum, rowptr, N);
    fill_kernel<<<(E + 255) / 256, 256, 0, stream>>>(src, tgt, rowptr, fillpos, csr_src, E);

    // layer 1
    gather_kernel<<<(N * 64 + 255) / 256, 256, 0, stream>>>(h, rowptr, csr_src, agg, N);
    layer_kernel<<<(N + 63) / 64, 256, 0, stream>>>(h, agg, w1l_f, w1r_f, b1_f, N);

    // layer 2
    gather_kernel<<<(N * 64 + 255) / 256, 256, 0, stream>>>(h, rowptr, csr_src, agg, N);
    layer_kernel<<<(N + 63) / 64, 256, 0, stream>>>(h, agg, w2l_f, w2r_f, b2_f, N);

    // pool + classify
    pool_classify_kernel<<<G, 256, 0, stream>>>(h, batch, wc_f, bc_f, d_out, flag, N);
}

// Round 4
// 516.008 us; speedup vs baseline: 5.9848x; 1.1629x over previous
//
#include <hip/hip_runtime.h>
#include <hip/hip_bf16.h>

// SPRGraphNet: embed -> 2x SAGEConv(mean) -> mean-pool per graph -> linear(64->10)
// Inputs detected fp32 (round 2). CSR + gather aggregation.
// Round 4: merged count+fill via atomic-rank trick; gather uses float4 lanes
// (16 lanes/edge, 4 edges/wave) + shfl reduction for 4x memory-level parallelism.

struct WParams {
    const void* p[10];
    int off[11];
};

__device__ __forceinline__ float loadf(const void* p, int i, int f32) {
    return f32 ? ((const float*)p)[i]
               : __bfloat162float(((const __hip_bfloat16*)p)[i]);
}

static __global__ void detect_kernel(const void* probe, int n_bf16, int* flag) {
    __shared__ int bad;
    if (threadIdx.x == 0) bad = 0;
    __syncthreads();
    const __hip_bfloat16* p = (const __hip_bfloat16*)probe;
    int lbad = 0;
    for (int i = threadIdx.x; i < n_bf16; i += blockDim.x) {
        float v = __bfloat162float(p[i]);
        if (!(fabsf(v) <= 100.0f)) lbad = 1;   // catches huge AND NaN
    }
    if (lbad) atomicOr(&bad, 1);
    __syncthreads();
    if (threadIdx.x == 0) *flag = bad;         // 1 => inputs are fp32
}

static __global__ void convert_kernel(WParams wp, const int* __restrict__ flag,
                                      float* __restrict__ dst, int total) {
    int gid = blockIdx.x * blockDim.x + threadIdx.x;
    if (gid >= total) return;
    int f32 = *flag;
    int s = 0;
    while (gid >= wp.off[s + 1]) ++s;
    dst[gid] = loadf(wp.p[s], gid - wp.off[s], f32);
}

static __global__ void embed_kernel(const int* __restrict__ x,
                                    const float* __restrict__ semb,
                                    const float* __restrict__ cemb,
                                    float* __restrict__ h, int n_nodes) {
    int gid = blockIdx.x * blockDim.x + threadIdx.x;
    int node = gid >> 6, col = gid & 63;
    if (node >= n_nodes) return;
    float v;
    if (col < 32) {
        int s = x[node * 2];
        v = semb[s * 32 + col];
    } else {
        int c = x[node * 2 + 1];
        v = cemb[c * 32 + (col - 32)];
    }
    h[node * 64 + col] = v;
}

// cnt[t] = in-degree; rank[e] = arrival order of edge e at its target.
static __global__ void count_rank_kernel(const int* __restrict__ tgt,
                                         int* __restrict__ cnt,
                                         int* __restrict__ rank, int n_edges) {
    int e = blockIdx.x * blockDim.x + threadIdx.x;
    if (e < n_edges) rank[e] = atomicAdd(&cnt[tgt[e]], 1);
}

// ---- prefix-sum (exclusive) over cnt -> rowptr[0..n], 3 kernels ----
static __global__ __launch_bounds__(256) void scan1_kernel(
        const int* __restrict__ cnt, int* __restrict__ tmp,
        int* __restrict__ bsum, int n) {
    __shared__ int s[256];
    int t = threadIdx.x;
    int i = blockIdx.x * 256 + t;
    s[t] = (i < n) ? cnt[i] : 0;
    __syncthreads();
#pragma unroll
    for (int d = 1; d < 256; d <<= 1) {
        int x = (t >= d) ? s[t - d] : 0;
        __syncthreads();
        s[t] += x;
        __syncthreads();
    }
    if (i < n) tmp[i] = s[t];                 // inclusive scan within block
    if (t == 255) bsum[blockIdx.x] = s[255];
}

static __global__ __launch_bounds__(1024) void scan2_kernel(
        int* __restrict__ bsum, int nb) {     // in-place inclusive scan, nb <= 1024
    __shared__ int s[1024];
    int t = threadIdx.x;
    s[t] = (t < nb) ? bsum[t] : 0;
    __syncthreads();
#pragma unroll
    for (int d = 1; d < 1024; d <<= 1) {
        int x = (t >= d) ? s[t - d] : 0;
        __syncthreads();
        s[t] += x;
        __syncthreads();
    }
    if (t < nb) bsum[t] = s[t];
}

static __global__ __launch_bounds__(256) void scan3_kernel(
        const int* __restrict__ tmp, const int* __restrict__ bsum,
        int* __restrict__ rowptr, int n) {
    int i = blockIdx.x * 256 + threadIdx.x;
    if (i >= n) return;
    int base = (blockIdx.x > 0) ? bsum[blockIdx.x - 1] : 0;
    rowptr[i + 1] = tmp[i] + base;            // exclusive: rowptr[k] = sum cnt[0..k-1]
    if (i == 0) rowptr[0] = 0;
}

// Atomic-free CSR fill: position comes from precomputed rank.
static __global__ void fill_kernel(const int* __restrict__ src,
                                   const int* __restrict__ tgt,
                                   const int* __restrict__ rowptr,
                                   const int* __restrict__ rank,
                                   int* __restrict__ csr_src, int n_edges) {
    int e = blockIdx.x * blockDim.x + threadIdx.x;
    if (e >= n_edges) return;
    int t = tgt[e];
    csr_src[rowptr[t] + rank[e]] = src[e];
}

// One wave per node. lane = 16*g + j: group g handles edges (i % 4 == g),
// lane loads float4 at cols [4j, 4j+4). Cross-group reduce via shfl_xor.
static __global__ __launch_bounds__(256) void gather_kernel(
        const float* __restrict__ h, const int* __restrict__ rowptr,
        const int* __restrict__ csr_src, float* __restrict__ agg, int n_nodes) {
    int node = (blockIdx.x * 256 + threadIdx.x) >> 6;
    int lane = threadIdx.x & 63;
    if (node >= n_nodes) return;
    int g = lane >> 4, j = lane & 15;
    int beg = rowptr[node], end = rowptr[node + 1];

    float4 acc = make_float4(0.f, 0.f, 0.f, 0.f);
    int i = beg + g;
    // unrolled: 4 edges in flight per lane (16 per wave)
    for (; i + 12 < end; i += 16) {
        int s0 = csr_src[i];
        int s1 = csr_src[i + 4];
        int s2 = csr_src[i + 8];
        int s3 = csr_src[i + 12];
        float4 v0 = *reinterpret_cast<const float4*>(h + (size_t)s0 * 64 + j * 4);
        float4 v1 = *reinterpret_cast<const float4*>(h + (size_t)s1 * 64 + j * 4);
        float4 v2 = *reinterpret_cast<const float4*>(h + (size_t)s2 * 64 + j * 4);
        float4 v3 = *reinterpret_cast<const float4*>(h + (size_t)s3 * 64 + j * 4);
        acc.x += v0.x + v1.x + v2.x + v3.x;
        acc.y += v0.y + v1.y + v2.y + v3.y;
        acc.z += v0.z + v1.z + v2.z + v3.z;
        acc.w += v0.w + v1.w + v2.w + v3.w;
    }
    for (; i < end; i += 4) {
        int s = csr_src[i];
        float4 v = *reinterpret_cast<const float4*>(h + (size_t)s * 64 + j * 4);
        acc.x += v.x; acc.y += v.y; acc.z += v.z; acc.w += v.w;
    }
    // reduce across the 4 edge-groups (lanes j, j+16, j+32, j+48)
#pragma unroll
    for (int m = 16; m < 64; m <<= 1) {
        acc.x += __shfl_xor(acc.x, m, 64);
        acc.y += __shfl_xor(acc.y, m, 64);
        acc.z += __shfl_xor(acc.z, m, 64);
        acc.w += __shfl_xor(acc.w, m, 64);
    }
    if (g == 0) {
        float inv = 1.0f / fmaxf((float)(end - beg), 1.0f);
        acc.x *= inv; acc.y *= inv; acc.z *= inv; acc.w *= inv;
        *reinterpret_cast<float4*>(agg + (size_t)node * 64 + j * 4) = acc;
    }
}

// h = relu(agg @ wl + h @ wr + b), in place (row i depends only on row i).
static __global__ __launch_bounds__(256) void layer_kernel(
        float* __restrict__ h, const float* __restrict__ agg,
        const float* __restrict__ wl, const float* __restrict__ wr,
        const float* __restrict__ b, int n_nodes) {
    __shared__ float wlS[64 * 64];
    __shared__ float wrS[64 * 64];
    __shared__ float aS[4][64];
    __shared__ float hS[4][64];
    int t = threadIdx.x;
    for (int i = t; i < 64 * 64; i += 256) {
        wlS[i] = wl[i];
        wrS[i] = wr[i];
    }
    int r = t >> 6, o = t & 63;
    float bias_o = b[o];
    __syncthreads();
    int base = blockIdx.x * 64;
    for (int it = 0; it < 16; ++it) {
        int node = base + it * 4 + r;
        if (node < n_nodes) {
            aS[r][o] = agg[(size_t)node * 64 + o];
            hS[r][o] = h[(size_t)node * 64 + o];
        }
        __syncthreads();
        if (node < n_nodes) {
            float acc = bias_o;
#pragma unroll
            for (int k = 0; k < 64; ++k) {
                acc = fmaf(aS[r][k], wlS[k * 64 + o], acc);
                acc = fmaf(hS[r][k], wrS[k * 64 + o], acc);
            }
            h[(size_t)node * 64 + o] = fmaxf(acc, 0.0f);
        }
        __syncthreads();
    }
}

// batch is sorted: binary-search [start,end) per graph; mean-pool then classify.
static __global__ __launch_bounds__(256) void pool_classify_kernel(
        const float* __restrict__ h, const int* __restrict__ batch,
        const float* __restrict__ wc, const float* __restrict__ bc,
        void* __restrict__ out, const int* __restrict__ flag, int n_nodes) {
    int g = blockIdx.x;
    int t = threadIdx.x;
    int lo = 0, hi = n_nodes;
    while (lo < hi) { int mid = (lo + hi) >> 1; if (batch[mid] < g) lo = mid + 1; else hi = mid; }
    int start = lo;
    hi = n_nodes;
    while (lo < hi) { int mid = (lo + hi) >> 1; if (batch[mid] < g + 1) lo = mid + 1; else hi = mid; }
    int end = lo;

    int r = t >> 6, o = t & 63;
    float partial = 0.0f;
    for (int n = start + r; n < end; n += 4) partial += h[(size_t)n * 64 + o];
    __shared__ float sred[4][64];
    __shared__ float pooled[64];
    sred[r][o] = partial;
    __syncthreads();
    if (r == 0) {
        float cntf = fmaxf((float)(end - start), 1.0f);
        pooled[o] = (sred[0][o] + sred[1][o] + sred[2][o] + sred[3][o]) / cntf;
    }
    __syncthreads();
    if (t < 10) {
        float acc = bc[t];
#pragma unroll
        for (int k = 0; k < 64; ++k)
            acc = fmaf(pooled[k], wc[k * 10 + t], acc);
        if (*flag) ((float*)out)[g * 10 + t] = acc;
        else       ((__hip_bfloat16*)out)[g * 10 + t] = __float2bfloat16(acc);
    }
}

extern "C" void kernel_launch(void* const* d_in, const int* in_sizes, int n_in,
                              void* d_out, int out_size, void* d_ws, size_t ws_size,
                              hipStream_t stream) {
    const int* x          = (const int*)d_in[0];
    const int* edge_index = (const int*)d_in[1];
    const int* batch      = (const int*)d_in[2];

    const int N = in_sizes[2];        // N_NODES
    const int E = in_sizes[1] / 2;    // edge_index is (2, E)
    const int G = out_size / 10;      // num_graphs
    const int NB = (N + 255) / 256;   // scan blocks (<=1024 required)

    // workspace layout (fp32 / int32)
    float* h       = (float*)d_ws;
    float* agg     = h + (size_t)N * 64;
    int*   cnt     = (int*)(agg + (size_t)N * 64);
    int*   rowptr  = cnt + N;                 // N+1
    int*   tmp     = rowptr + (N + 1);        // N
    int*   bsum    = tmp + N;                 // NB
    int*   rank    = bsum + NB;               // E
    int*   csr_src = rank + E;                // E
    float* wbuf    = (float*)(csr_src + E);

    WParams wp;
    int off = 0;
    for (int i = 0; i < 10; ++i) {
        wp.p[i] = d_in[4 + i];
        wp.off[i] = off;
        off += in_sizes[4 + i];
    }
    wp.off[10] = off;
    const int wtotal = off;

    float* semb_f = wbuf + wp.off[0];
    float* cemb_f = wbuf + wp.off[1];
    float* w1l_f  = wbuf + wp.off[2];
    float* w1r_f  = wbuf + wp.off[3];
    float* b1_f   = wbuf + wp.off[4];
    float* w2l_f  = wbuf + wp.off[5];
    float* w2r_f  = wbuf + wp.off[6];
    float* b2_f   = wbuf + wp.off[7];
    float* wc_f   = wbuf + wp.off[8];
    float* bc_f   = wbuf + wp.off[9];
    int*   flag   = (int*)(wbuf + wtotal);

    const int* src = edge_index;
    const int* tgt = edge_index + E;

    detect_kernel<<<1, 256, 0, stream>>>(d_in[4], 1024, flag);
    convert_kernel<<<(wtotal + 255) / 256, 256, 0, stream>>>(wp, flag, wbuf, wtotal);

    // zero cnt
    hipMemsetAsync(cnt, 0, (size_t)N * sizeof(int), stream);

    embed_kernel<<<(N * 64 + 255) / 256, 256, 0, stream>>>(x, semb_f, cemb_f, h, N);
    count_rank_kernel<<<(E + 255) / 256, 256, 0, stream>>>(tgt, cnt, rank, E);

    // CSR build
    scan1_kernel<<<NB, 256, 0, stream>>>(cnt, tmp, bsum, N);
    scan2_kernel<<<1, 1024, 0, stream>>>(bsum, NB);
    scan3_kernel<<<NB, 256, 0, stream>>>(tmp, bsum, rowptr, N);
    fill_kernel<<<(E + 255) / 256, 256, 0, stream>>>(src, tgt, rowptr, rank, csr_src, E);

    // layer 1
    gather_kernel<<<(N * 64 + 255) / 256, 256, 0, stream>>>(h, rowptr, csr_src, agg, N);
    layer_kernel<<<(N + 63) / 64, 256, 0, stream>>>(h, agg, w1l_f, w1r_f, b1_f, N);

    // layer 2
    gather_kernel<<<(N * 64 + 255) / 256, 256, 0, stream>>>(h, rowptr, csr_src, agg, N);
    layer_kernel<<<(N + 63) / 64, 256, 0, stream>>>(h, agg, w2l_f, w2r_f, b2_f, N);

    // pool + classify
    pool_classify_kernel<<<G, 256, 0, stream>>>(h, batch, wc_f, bc_f, d_out, flag, N);
}

// Round 5
// 399.058 us; speedup vs baseline: 7.7387x; 1.2931x over previous
//
#include <hip/hip_runtime.h>
#include <hip/hip_bf16.h>

// SPRGraphNet: embed -> 2x SAGEConv(mean) -> mean-pool per graph -> linear(64->10)
// Inputs detected fp32 (round 2). CSR + gather aggregation (round 3/4).
// Round 5: layer_kernel rewritten as 4x4 register-tiled GEMM (round 4 showed
// it LDS-b32-serialized at 24.7% VALUBusy, 95 us).

struct WParams {
    const void* p[10];
    int off[11];
};

__device__ __forceinline__ float loadf(const void* p, int i, int f32) {
    return f32 ? ((const float*)p)[i]
               : __bfloat162float(((const __hip_bfloat16*)p)[i]);
}

static __global__ void detect_kernel(const void* probe, int n_bf16, int* flag) {
    __shared__ int bad;
    if (threadIdx.x == 0) bad = 0;
    __syncthreads();
    const __hip_bfloat16* p = (const __hip_bfloat16*)probe;
    int lbad = 0;
    for (int i = threadIdx.x; i < n_bf16; i += blockDim.x) {
        float v = __bfloat162float(p[i]);
        if (!(fabsf(v) <= 100.0f)) lbad = 1;   // catches huge AND NaN
    }
    if (lbad) atomicOr(&bad, 1);
    __syncthreads();
    if (threadIdx.x == 0) *flag = bad;         // 1 => inputs are fp32
}

static __global__ void convert_kernel(WParams wp, const int* __restrict__ flag,
                                      float* __restrict__ dst, int total) {
    int gid = blockIdx.x * blockDim.x + threadIdx.x;
    if (gid >= total) return;
    int f32 = *flag;
    int s = 0;
    while (gid >= wp.off[s + 1]) ++s;
    dst[gid] = loadf(wp.p[s], gid - wp.off[s], f32);
}

static __global__ void embed_kernel(const int* __restrict__ x,
                                    const float* __restrict__ semb,
                                    const float* __restrict__ cemb,
                                    float* __restrict__ h, int n_nodes) {
    int gid = blockIdx.x * blockDim.x + threadIdx.x;
    int node = gid >> 6, col = gid & 63;
    if (node >= n_nodes) return;
    float v;
    if (col < 32) {
        int s = x[node * 2];
        v = semb[s * 32 + col];
    } else {
        int c = x[node * 2 + 1];
        v = cemb[c * 32 + (col - 32)];
    }
    h[node * 64 + col] = v;
}

// cnt[t] = in-degree; rank[e] = arrival order of edge e at its target.
static __global__ void count_rank_kernel(const int* __restrict__ tgt,
                                         int* __restrict__ cnt,
                                         int* __restrict__ rank, int n_edges) {
    int e = blockIdx.x * blockDim.x + threadIdx.x;
    if (e < n_edges) rank[e] = atomicAdd(&cnt[tgt[e]], 1);
}

// ---- prefix-sum (exclusive) over cnt -> rowptr[0..n], 3 kernels ----
static __global__ __launch_bounds__(256) void scan1_kernel(
        const int* __restrict__ cnt, int* __restrict__ tmp,
        int* __restrict__ bsum, int n) {
    __shared__ int s[256];
    int t = threadIdx.x;
    int i = blockIdx.x * 256 + t;
    s[t] = (i < n) ? cnt[i] : 0;
    __syncthreads();
#pragma unroll
    for (int d = 1; d < 256; d <<= 1) {
        int x = (t >= d) ? s[t - d] : 0;
        __syncthreads();
        s[t] += x;
        __syncthreads();
    }
    if (i < n) tmp[i] = s[t];                 // inclusive scan within block
    if (t == 255) bsum[blockIdx.x] = s[255];
}

static __global__ __launch_bounds__(1024) void scan2_kernel(
        int* __restrict__ bsum, int nb) {     // in-place inclusive scan, nb <= 1024
    __shared__ int s[1024];
    int t = threadIdx.x;
    s[t] = (t < nb) ? bsum[t] : 0;
    __syncthreads();
#pragma unroll
    for (int d = 1; d < 1024; d <<= 1) {
        int x = (t >= d) ? s[t - d] : 0;
        __syncthreads();
        s[t] += x;
        __syncthreads();
    }
    if (t < nb) bsum[t] = s[t];
}

static __global__ __launch_bounds__(256) void scan3_kernel(
        const int* __restrict__ tmp, const int* __restrict__ bsum,
        int* __restrict__ rowptr, int n) {
    int i = blockIdx.x * 256 + threadIdx.x;
    if (i >= n) return;
    int base = (blockIdx.x > 0) ? bsum[blockIdx.x - 1] : 0;
    rowptr[i + 1] = tmp[i] + base;            // exclusive: rowptr[k] = sum cnt[0..k-1]
    if (i == 0) rowptr[0] = 0;
}

// Atomic-free CSR fill: position comes from precomputed rank.
static __global__ void fill_kernel(const int* __restrict__ src,
                                   const int* __restrict__ tgt,
                                   const int* __restrict__ rowptr,
                                   const int* __restrict__ rank,
                                   int* __restrict__ csr_src, int n_edges) {
    int e = blockIdx.x * blockDim.x + threadIdx.x;
    if (e >= n_edges) return;
    int t = tgt[e];
    csr_src[rowptr[t] + rank[e]] = src[e];
}

// One wave per node. lane = 16*g + j: group g handles edges (i % 4 == g),
// lane loads float4 at cols [4j, 4j+4). Cross-group reduce via shfl_xor.
static __global__ __launch_bounds__(256) void gather_kernel(
        const float* __restrict__ h, const int* __restrict__ rowptr,
        const int* __restrict__ csr_src, float* __restrict__ agg, int n_nodes) {
    int node = (blockIdx.x * 256 + threadIdx.x) >> 6;
    int lane = threadIdx.x & 63;
    if (node >= n_nodes) return;
    int g = lane >> 4, j = lane & 15;
    int beg = rowptr[node], end = rowptr[node + 1];

    float4 acc = make_float4(0.f, 0.f, 0.f, 0.f);
    int i = beg + g;
    // unrolled: 4 edges in flight per lane (16 per wave)
    for (; i + 12 < end; i += 16) {
        int s0 = csr_src[i];
        int s1 = csr_src[i + 4];
        int s2 = csr_src[i + 8];
        int s3 = csr_src[i + 12];
        float4 v0 = *reinterpret_cast<const float4*>(h + (size_t)s0 * 64 + j * 4);
        float4 v1 = *reinterpret_cast<const float4*>(h + (size_t)s1 * 64 + j * 4);
        float4 v2 = *reinterpret_cast<const float4*>(h + (size_t)s2 * 64 + j * 4);
        float4 v3 = *reinterpret_cast<const float4*>(h + (size_t)s3 * 64 + j * 4);
        acc.x += v0.x + v1.x + v2.x + v3.x;
        acc.y += v0.y + v1.y + v2.y + v3.y;
        acc.z += v0.z + v1.z + v2.z + v3.z;
        acc.w += v0.w + v1.w + v2.w + v3.w;
    }
    for (; i < end; i += 4) {
        int s = csr_src[i];
        float4 v = *reinterpret_cast<const float4*>(h + (size_t)s * 64 + j * 4);
        acc.x += v.x; acc.y += v.y; acc.z += v.z; acc.w += v.w;
    }
    // reduce across the 4 edge-groups (lanes j, j+16, j+32, j+48)
#pragma unroll
    for (int m = 16; m < 64; m <<= 1) {
        acc.x += __shfl_xor(acc.x, m, 64);
        acc.y += __shfl_xor(acc.y, m, 64);
        acc.z += __shfl_xor(acc.z, m, 64);
        acc.w += __shfl_xor(acc.w, m, 64);
    }
    if (g == 0) {
        float inv = 1.0f / fmaxf((float)(end - beg), 1.0f);
        acc.x *= inv; acc.y *= inv; acc.z *= inv; acc.w *= inv;
        *reinterpret_cast<float4*>(agg + (size_t)node * 64 + j * 4) = acc;
    }
}

// h = relu([agg | h] @ [wl; wr] + b), in place. 4x4 register tiling.
// Block: 256 threads = 16x16; tile = 64 nodes x 64 cols.
static __global__ __launch_bounds__(256) void layer_kernel(
        float* __restrict__ h, const float* __restrict__ agg,
        const float* __restrict__ wl, const float* __restrict__ wr,
        const float* __restrict__ b, int n_nodes) {
    __shared__ float inS[64][132];   // [node][k], +4 pad: 16B-aligned rows, 2-way banks
    __shared__ float wS[128][64];    // [k][col], rows 0..63 = wl, 64..127 = wr
    int t = threadIdx.x;
    int base = blockIdx.x * 64;

    // stage weights: 2048 float4 total
    const float4* wl4 = (const float4*)wl;
    const float4* wr4 = (const float4*)wr;
#pragma unroll
    for (int r = 0; r < 4; ++r) {
        int i = t + 256 * r;                 // 0..1023 float4 index within 64x64
        int k = i >> 4, c = (i & 15) * 4;
        *(float4*)&wS[k][c] = wl4[i];
        *(float4*)&wS[64 + k][c] = wr4[i];
    }
    // stage inputs: inS[n][0..63] = agg row, inS[n][64..127] = h row
#pragma unroll
    for (int r = 0; r < 4; ++r) {
        int i = t + 256 * r;                 // 0..1023
        int n = i >> 4, c = (i & 15) * 4;
        int node = base + n;
        float4 va = make_float4(0.f, 0.f, 0.f, 0.f);
        float4 vh = make_float4(0.f, 0.f, 0.f, 0.f);
        if (node < n_nodes) {
            va = *(const float4*)&agg[(size_t)node * 64 + c];
            vh = *(const float4*)&h[(size_t)node * 64 + c];
        }
        *(float4*)&inS[n][c] = va;
        *(float4*)&inS[n][64 + c] = vh;
    }
    __syncthreads();

    int tx = t & 15, ty = t >> 4;
    int c0 = tx * 4, n0 = ty * 4;
    float4 bias = *(const float4*)&b[c0];
    float acc[4][4];
#pragma unroll
    for (int i = 0; i < 4; ++i) {
        acc[i][0] = bias.x; acc[i][1] = bias.y;
        acc[i][2] = bias.z; acc[i][3] = bias.w;
    }

#pragma unroll 4
    for (int k = 0; k < 128; k += 4) {
        float4 a0 = *(const float4*)&inS[n0 + 0][k];
        float4 a1 = *(const float4*)&inS[n0 + 1][k];
        float4 a2 = *(const float4*)&inS[n0 + 2][k];
        float4 a3 = *(const float4*)&inS[n0 + 3][k];
        float4 w0 = *(const float4*)&wS[k + 0][c0];
        float4 w1 = *(const float4*)&wS[k + 1][c0];
        float4 w2 = *(const float4*)&wS[k + 2][c0];
        float4 w3 = *(const float4*)&wS[k + 3][c0];
#define ROW(i, ai)                                                        \
        acc[i][0] = fmaf(ai.x, w0.x, fmaf(ai.y, w1.x, fmaf(ai.z, w2.x,    \
                    fmaf(ai.w, w3.x, acc[i][0]))));                       \
        acc[i][1] = fmaf(ai.x, w0.y, fmaf(ai.y, w1.y, fmaf(ai.z, w2.y,    \
                    fmaf(ai.w, w3.y, acc[i][1]))));                       \
        acc[i][2] = fmaf(ai.x, w0.z, fmaf(ai.y, w1.z, fmaf(ai.z, w2.z,    \
                    fmaf(ai.w, w3.z, acc[i][2]))));                       \
        acc[i][3] = fmaf(ai.x, w0.w, fmaf(ai.y, w1.w, fmaf(ai.z, w2.w,    \
                    fmaf(ai.w, w3.w, acc[i][3]))));
        ROW(0, a0) ROW(1, a1) ROW(2, a2) ROW(3, a3)
#undef ROW
    }

#pragma unroll
    for (int i = 0; i < 4; ++i) {
        int node = base + n0 + i;
        if (node < n_nodes) {
            float4 o;
            o.x = fmaxf(acc[i][0], 0.f);
            o.y = fmaxf(acc[i][1], 0.f);
            o.z = fmaxf(acc[i][2], 0.f);
            o.w = fmaxf(acc[i][3], 0.f);
            *(float4*)&h[(size_t)node * 64 + c0] = o;
        }
    }
}

// batch is sorted: binary-search [start,end) per graph; mean-pool then classify.
static __global__ __launch_bounds__(256) void pool_classify_kernel(
        const float* __restrict__ h, const int* __restrict__ batch,
        const float* __restrict__ wc, const float* __restrict__ bc,
        void* __restrict__ out, const int* __restrict__ flag, int n_nodes) {
    int g = blockIdx.x;
    int t = threadIdx.x;
    int lo = 0, hi = n_nodes;
    while (lo < hi) { int mid = (lo + hi) >> 1; if (batch[mid] < g) lo = mid + 1; else hi = mid; }
    int start = lo;
    hi = n_nodes;
    while (lo < hi) { int mid = (lo + hi) >> 1; if (batch[mid] < g + 1) lo = mid + 1; else hi = mid; }
    int end = lo;

    int r = t >> 6, o = t & 63;
    float partial = 0.0f;
    for (int n = start + r; n < end; n += 4) partial += h[(size_t)n * 64 + o];
    __shared__ float sred[4][64];
    __shared__ float pooled[64];
    sred[r][o] = partial;
    __syncthreads();
    if (r == 0) {
        float cntf = fmaxf((float)(end - start), 1.0f);
        pooled[o] = (sred[0][o] + sred[1][o] + sred[2][o] + sred[3][o]) / cntf;
    }
    __syncthreads();
    if (t < 10) {
        float acc = bc[t];
#pragma unroll
        for (int k = 0; k < 64; ++k)
            acc = fmaf(pooled[k], wc[k * 10 + t], acc);
        if (*flag) ((float*)out)[g * 10 + t] = acc;
        else       ((__hip_bfloat16*)out)[g * 10 + t] = __float2bfloat16(acc);
    }
}

extern "C" void kernel_launch(void* const* d_in, const int* in_sizes, int n_in,
                              void* d_out, int out_size, void* d_ws, size_t ws_size,
                              hipStream_t stream) {
    const int* x          = (const int*)d_in[0];
    const int* edge_index = (const int*)d_in[1];
    const int* batch      = (const int*)d_in[2];

    const int N = in_sizes[2];        // N_NODES
    const int E = in_sizes[1] / 2;    // edge_index is (2, E)
    const int G = out_size / 10;      // num_graphs
    const int NB = (N + 255) / 256;   // scan blocks (<=1024 required)

    // workspace layout (fp32 / int32)
    float* h       = (float*)d_ws;
    float* agg     = h + (size_t)N * 64;
    int*   cnt     = (int*)(agg + (size_t)N * 64);
    int*   rowptr  = cnt + N;                 // N+1
    int*   tmp     = rowptr + (N + 1);        // N
    int*   bsum    = tmp + N;                 // NB
    int*   rank    = bsum + NB;               // E
    int*   csr_src = rank + E;                // E
    float* wbuf    = (float*)(csr_src + E);

    WParams wp;
    int off = 0;
    for (int i = 0; i < 10; ++i) {
        wp.p[i] = d_in[4 + i];
        wp.off[i] = off;
        off += in_sizes[4 + i];
    }
    wp.off[10] = off;
    const int wtotal = off;

    float* semb_f = wbuf + wp.off[0];
    float* cemb_f = wbuf + wp.off[1];
    float* w1l_f  = wbuf + wp.off[2];
    float* w1r_f  = wbuf + wp.off[3];
    float* b1_f   = wbuf + wp.off[4];
    float* w2l_f  = wbuf + wp.off[5];
    float* w2r_f  = wbuf + wp.off[6];
    float* b2_f   = wbuf + wp.off[7];
    float* wc_f   = wbuf + wp.off[8];
    float* bc_f   = wbuf + wp.off[9];
    int*   flag   = (int*)(wbuf + wtotal);

    const int* src = edge_index;
    const int* tgt = edge_index + E;

    detect_kernel<<<1, 256, 0, stream>>>(d_in[4], 1024, flag);
    convert_kernel<<<(wtotal + 255) / 256, 256, 0, stream>>>(wp, flag, wbuf, wtotal);

    // zero cnt
    hipMemsetAsync(cnt, 0, (size_t)N * sizeof(int), stream);

    embed_kernel<<<(N * 64 + 255) / 256, 256, 0, stream>>>(x, semb_f, cemb_f, h, N);
    count_rank_kernel<<<(E + 255) / 256, 256, 0, stream>>>(tgt, cnt, rank, E);

    // CSR build
    scan1_kernel<<<NB, 256, 0, stream>>>(cnt, tmp, bsum, N);
    scan2_kernel<<<1, 1024, 0, stream>>>(bsum, NB);
    scan3_kernel<<<NB, 256, 0, stream>>>(tmp, bsum, rowptr, N);
    fill_kernel<<<(E + 255) / 256, 256, 0, stream>>>(src, tgt, rowptr, rank, csr_src, E);

    // layer 1
    gather_kernel<<<(N * 64 + 255) / 256, 256, 0, stream>>>(h, rowptr, csr_src, agg, N);
    layer_kernel<<<(N + 63) / 64, 256, 0, stream>>>(h, agg, w1l_f, w1r_f, b1_f, N);

    // layer 2
    gather_kernel<<<(N * 64 + 255) / 256, 256, 0, stream>>>(h, rowptr, csr_src, agg, N);
    layer_kernel<<<(N + 63) / 64, 256, 0, stream>>>(h, agg, w2l_f, w2r_f, b2_f, N);

    // pool + classify
    pool_classify_kernel<<<G, 256, 0, stream>>>(h, batch, wc_f, bc_f, d_out, flag, N);
}